// Round 1
// baseline (235.717 us; speedup 1.0000x reference)
//
#include <hip/hip_runtime.h>
#include <hip/hip_bf16.h>

#define TSC_OUT_LEN 16384
#define TSC_ENC_LEN 16368   // 16384 - 16384/1024

// out[b,j] = sum_{e=1..10} data[b, off_e + (j>>e)] * weights[(2^e-1) + (j & (2^e-1))]
//            + sum_e bias[e-1]
// off_e = OUT_LEN - (OUT_LEN >> (e-1)).
// One thread computes 8 consecutive outputs (j0 = 8*gid):
//  - e=1: float4 data load (bulk of read bytes), weights wl[2],wl[3]
//  - e=2: float2 data load, one float4 weight run
//  - e>=3: scalar data load (wave-coalesced/broadcast), 8 consecutive weights
// Weights staged in LDS shifted +1 so runs starting at 2^e-1 become 16B-aligned.
__global__ __launch_bounds__(256) void tsc_transpose_kernel(
    const float* __restrict__ data,
    const float* __restrict__ weights,
    const float* __restrict__ bias,
    float* __restrict__ out)
{
    __shared__ float wl[2048];
    const int tid = threadIdx.x;
    for (int i = tid; i < 2047; i += 256) wl[i + 1] = weights[i];
    if (tid == 0) wl[0] = 0.0f;
    __syncthreads();

    // Sum of all per-scale biases — a single constant added to every output.
    float bs = 0.0f;
#pragma unroll
    for (int i = 0; i < 10; ++i) bs += bias[i];

    const int b    = blockIdx.x >> 3;          // 8 tiles of 2048 outputs per row
    const int tile = (blockIdx.x & 7) << 11;   // tile * 2048
    const int j0   = tile + (tid << 3);        // 8 consecutive outputs, 8-aligned
    const float* drow = data + (size_t)b * TSC_ENC_LEN;

    float acc[8];
#pragma unroll
    for (int k = 0; k < 8; ++k) acc[k] = bs;

    // e = 1 (w=2, off=0): data indices j0/2 .. j0/2+3 (j0/2 is 4-aligned)
    {
        const float4 d4 = *reinterpret_cast<const float4*>(drow + (j0 >> 1));
        const float w1 = wl[2], w2 = wl[3];
        acc[0] += d4.x * w1; acc[1] += d4.x * w2;
        acc[2] += d4.y * w1; acc[3] += d4.y * w2;
        acc[4] += d4.z * w1; acc[5] += d4.z * w2;
        acc[6] += d4.w * w1; acc[7] += d4.w * w2;
    }
    // e = 2 (w=4, off=8192): j0&3 == 0 so weight run = wl[4..7]
    {
        const float2 d2 = *reinterpret_cast<const float2*>(drow + 8192 + (j0 >> 2));
        const float4 kv = *reinterpret_cast<const float4*>(&wl[4]);
        acc[0] += d2.x * kv.x; acc[1] += d2.x * kv.y;
        acc[2] += d2.x * kv.z; acc[3] += d2.x * kv.w;
        acc[4] += d2.y * kv.x; acc[5] += d2.y * kv.y;
        acc[6] += d2.y * kv.z; acc[7] += d2.y * kv.w;
    }
    // e = 3..10: one shared data coeff per thread, 8 consecutive weights
#pragma unroll
    for (int e = 3; e <= 10; ++e) {
        const int w   = 1 << e;
        const int off = TSC_OUT_LEN - (TSC_OUT_LEN >> (e - 1));
        const float c = drow[off + (j0 >> e)];
        const int  kb = w + (j0 & (w - 1));   // (w-1) + (j0&(w-1)) + 1(shift); 8-aligned
        const float4 k0 = *reinterpret_cast<const float4*>(&wl[kb]);
        const float4 k1 = *reinterpret_cast<const float4*>(&wl[kb + 4]);
        acc[0] += c * k0.x; acc[1] += c * k0.y;
        acc[2] += c * k0.z; acc[3] += c * k0.w;
        acc[4] += c * k1.x; acc[5] += c * k1.y;
        acc[6] += c * k1.z; acc[7] += c * k1.w;
    }

    float4* o = reinterpret_cast<float4*>(out + (size_t)b * TSC_OUT_LEN + j0);
    o[0] = make_float4(acc[0], acc[1], acc[2], acc[3]);
    o[1] = make_float4(acc[4], acc[5], acc[6], acc[7]);
}

extern "C" void kernel_launch(void* const* d_in, const int* in_sizes, int n_in,
                              void* d_out, int out_size, void* d_ws, size_t ws_size,
                              hipStream_t stream) {
    const float* data    = (const float*)d_in[0];
    const float* weights = (const float*)d_in[1];
    const float* bias    = (const float*)d_in[2];
    float* out = (float*)d_out;

    const int B = in_sizes[0] / TSC_ENC_LEN;   // 2048
    dim3 grid(B * 8);                          // 8 tiles of 2048 outputs per row
    dim3 block(256);
    tsc_transpose_kernel<<<grid, block, 0, stream>>>(data, weights, bias, out);
}